// Round 12
// baseline (210.754 us; speedup 1.0000x reference)
//
#include <hip/hip_runtime.h>
#include <stdint.h>

#define IN_F 256
#define OUT_F 128
#define NCOLS 1024   // GEMM cols: 768 slices + 128 sum-slice + 128 self
#define PROWB 1152   // P row bytes: 896 fp8 (slices+sum) + 256 bf16 self
#define BM 64
#define BN 128
#define BK 32

using bf16x8 = __attribute__((ext_vector_type(8))) __bf16;
using f32x4  = __attribute__((ext_vector_type(4))) float;
using f32x2  = __attribute__((ext_vector_type(2))) float;

static __device__ __forceinline__ unsigned short f2bf(float f) {
    unsigned u = __float_as_uint(f);
    u = u + 0x7fffu + ((u >> 16) & 1u);   // RNE
    return (unsigned short)(u >> 16);
}
static __device__ __forceinline__ float bf_lo(unsigned u) { return __uint_as_float(u << 16); }
static __device__ __forceinline__ float bf_hi(unsigned u) { return __uint_as_float(u & 0xffff0000u); }

static __device__ __forceinline__ void async_load16(const void* g, void* l) {
    __builtin_amdgcn_global_load_lds(
        (__attribute__((address_space(1))) void*)g,
        (__attribute__((address_space(3))) void*)l,
        16, 0, 0);
}

// ---- h (f32) -> bf16 ----
__global__ void k_conv_h(const float* __restrict__ h, unsigned short* __restrict__ hb, int total8) {
    int i = blockIdx.x * blockDim.x + threadIdx.x;
    if (i >= total8) return;
    const float4* src = ((const float4*)h) + (size_t)i * 2;
    float4 a = src[0], b = src[1];
    union { unsigned short us[8]; uint4 v; } u;
    u.us[0] = f2bf(a.x); u.us[1] = f2bf(a.y); u.us[2] = f2bf(a.z); u.us[3] = f2bf(a.w);
    u.us[4] = f2bf(b.x); u.us[5] = f2bf(b.y); u.us[6] = f2bf(b.z); u.us[7] = f2bf(b.w);
    ((uint4*)hb)[i] = u.v;
}

// ---- Wt[1024][256] = [W_node | sum(slices) | W_self]^T bf16; bvec[1024] ----
__global__ void k_conv_w(const float* __restrict__ Wn, const float* __restrict__ Ws,
                         const float* __restrict__ bn, const float* __restrict__ bs,
                         unsigned short* __restrict__ Wt, float* __restrict__ bvec, int total) {
    int i = blockIdx.x * blockDim.x + threadIdx.x;   // i = k*1024 + c
    if (i >= total) return;
    int k = i >> 10, c = i & 1023;
    float v;
    if (c < 768) {
        v = Wn[(size_t)k * 768 + c];
    } else if (c < 896) {
        int j = c - 768; v = 0.f;
#pragma unroll
        for (int s = 0; s < 6; ++s) v += Wn[(size_t)k * 768 + s * 128 + j];
    } else {
        v = Ws[(size_t)k * 128 + (c - 896)];
    }
    Wt[(size_t)c * IN_F + k] = f2bf(v);

    if (i < NCOLS) {
        float b;
        if (i < 768) b = bn[i];
        else if (i < 896) {
            int j = i - 768; b = 0.f;
#pragma unroll
            for (int s = 0; s < 6; ++s) b += bn[s * 128 + j];
        } else b = bs[i - 896];
        bvec[i] = b;
    }
}

// ---- GEMM: R11 pipeline; epilogue = direct permuted stores (no LDS staging) ----
__global__ void __launch_bounds__(256) k_gemm(
    const unsigned short* __restrict__ hb,
    const unsigned short* __restrict__ Wt,
    const float* __restrict__ bvec,
    const float* __restrict__ norm,
    char* __restrict__ PG, int N, int rowsPerXcd)
{
    __shared__ char lds[(BM + BN) * BK * 2];       // 12 KB (A 4 KB, B 8 KB)
    char* Ab = lds;
    char* Bb = lds + BM * BK * 2;

    const int f  = blockIdx.x;
    const int xc = f & 7;
    const int j  = f >> 3;
    const int rs = xc * rowsPerXcd + (j >> 3);
    const int ct = j & 7;
    const int r0 = rs * BM;
    if (r0 >= N) return;
    const int c0 = ct * BN;

    const int tid = threadIdx.x;
    const int wid = tid >> 6, lane = tid & 63;
    const int lrow = lane & 15, s = lane >> 4;
    const int wr = wid >> 1, wc = wid & 1;

    const int arow = tid >> 2;
    const int achunk = (tid & 3) ^ ((arow >> 1) & 3);
    int agrow = r0 + arow; if (agrow >= N) agrow = N - 1;
    const unsigned short* aseg = hb + (size_t)agrow * IN_F + achunk * 8;

    const int bcol0 = tid >> 2;
    const int bchunk0 = (tid & 3) ^ ((bcol0 >> 1) & 3);
    const unsigned short* bseg0 = Wt + (size_t)(c0 + bcol0) * IN_F + bchunk0 * 8;
    const int idx1 = tid + 256;
    const int bcol1 = idx1 >> 2;
    const int bchunk1 = (idx1 & 3) ^ ((bcol1 >> 1) & 3);
    const unsigned short* bseg1 = Wt + (size_t)(c0 + bcol1) * IN_F + bchunk1 * 8;

    int a_off[2], b_off[4];
#pragma unroll
    for (int m = 0; m < 2; ++m) {
        int rl = wr * 32 + m * 16 + lrow;
        a_off[m] = rl * 64 + ((s ^ ((rl >> 1) & 3)) << 4);
    }
#pragma unroll
    for (int n = 0; n < 4; ++n) {
        int cl = wc * 64 + n * 16 + lrow;
        b_off[n] = cl * 64 + ((s ^ ((cl >> 1) & 3)) << 4);
    }

    float nrmv[2][4];
#pragma unroll
    for (int m = 0; m < 2; ++m)
#pragma unroll
        for (int r = 0; r < 4; ++r) {
            int rg = r0 + wr * 32 + m * 16 + s * 4 + r;
            nrmv[m][r] = norm[rg < N ? rg : N - 1];
        }

    f32x4 acc[2][4] = {};

    for (int kk = 0; kk < IN_F / BK; ++kk) {
        async_load16(aseg + kk * BK, Ab + tid * 16);
        async_load16(bseg0 + kk * BK, Bb + tid * 16);
        async_load16(bseg1 + kk * BK, Bb + (tid + 256) * 16);
        __syncthreads();

        bf16x8 af[2], bfv[4];
#pragma unroll
        for (int m = 0; m < 2; ++m) af[m] = *(const bf16x8*)(Ab + a_off[m]);
#pragma unroll
        for (int n = 0; n < 4; ++n) bfv[n] = *(const bf16x8*)(Bb + b_off[n]);
#pragma unroll
        for (int m = 0; m < 2; ++m)
#pragma unroll
            for (int n = 0; n < 4; ++n)
                acc[m][n] = __builtin_amdgcn_mfma_f32_16x16x32_bf16(af[m], bfv[n], acc[m][n], 0, 0, 0);
        __syncthreads();
    }

    float bvn[4];
#pragma unroll
    for (int n = 0; n < 4; ++n) bvn[n] = bvec[c0 + wc * 64 + n * 16 + lrow];

    if (ct < 7) {
        // fp8 tile in packed fragment order: dword d = wc*16+lrow, byte b -> col (d>>4)*64+b*16+(d&15)
#pragma unroll
        for (int m = 0; m < 2; ++m) {
#pragma unroll
            for (int r = 0; r < 4; ++r) {
                const int rg = r0 + wr * 32 + m * 16 + s * 4 + r;
                if (rg >= N) continue;
                const float sc = nrmv[m][r];
                float v0 = (acc[m][0][r] + bvn[0]) * sc;
                float v1 = (acc[m][1][r] + bvn[1]) * sc;
                float v2 = (acc[m][2][r] + bvn[2]) * sc;
                float v3 = (acc[m][3][r] + bvn[3]) * sc;
                int pk = __builtin_amdgcn_cvt_pk_fp8_f32(v0, v1, 0, false);
                pk = __builtin_amdgcn_cvt_pk_fp8_f32(v2, v3, pk, true);
                *(int*)(PG + (size_t)rg * PROWB + ct * 128 + (wc * 16 + lrow) * 4) = pk;
            }
        }
    } else {
        // bf16 self tile, permuted: dword L=wc*32+2*lrow holds cols (cA(L), cA(L)+16)
#pragma unroll
        for (int m = 0; m < 2; ++m) {
#pragma unroll
            for (int r = 0; r < 4; ++r) {
                const int rg = r0 + wr * 32 + m * 16 + s * 4 + r;
                if (rg >= N) continue;
                float v0 = acc[m][0][r] + bvn[0];
                float v1 = acc[m][1][r] + bvn[1];
                float v2 = acc[m][2][r] + bvn[2];
                float v3 = acc[m][3][r] + bvn[3];
                uint2 dd;
                dd.x = (unsigned)f2bf(v0) | ((unsigned)f2bf(v1) << 16);
                dd.y = (unsigned)f2bf(v2) | ((unsigned)f2bf(v3) << 16);
                *(uint2*)(PG + (size_t)rg * PROWB + 896 + (wc * 32 + 2 * lrow) * 4) = dd;
            }
        }
    }
}

// ---- histogram over dst (edge counts) ----
__global__ void k_hist(const int* __restrict__ dst, int* __restrict__ counts, int E) {
    int e = blockIdx.x * blockDim.x + threadIdx.x;
    if (e < E) atomicAdd(&counts[dst[e]], 1);
}

// ---- 3-phase exclusive scan over counts[N] ----
__global__ void __launch_bounds__(256) k_scan_a(const int* __restrict__ counts,
                                                int* __restrict__ offs,
                                                int* __restrict__ bsum, int N) {
    __shared__ int sm[256];
    int tid = threadIdx.x;
    int i = blockIdx.x * 256 + tid;
    int v = (i < N) ? counts[i] : 0;
    sm[tid] = v;
    __syncthreads();
#pragma unroll
    for (int st = 1; st < 256; st <<= 1) {
        int t = (tid >= st) ? sm[tid - st] : 0;
        __syncthreads();
        sm[tid] += t;
        __syncthreads();
    }
    if (i < N) offs[i] = sm[tid] - v;
    if (tid == 255) bsum[blockIdx.x] = sm[255];
}

__global__ void __launch_bounds__(256) k_scan_b(int* __restrict__ bsum, int NB) {
    __shared__ int sm[256];
    int tid = threadIdx.x;
    int v = (tid < NB) ? bsum[tid] : 0;
    sm[tid] = v;
    __syncthreads();
#pragma unroll
    for (int st = 1; st < 256; st <<= 1) {
        int t = (tid >= st) ? sm[tid - st] : 0;
        __syncthreads();
        sm[tid] += t;
        __syncthreads();
    }
    if (tid < NB) bsum[tid] = sm[tid] - v;
}

__global__ void k_scan_c(int* __restrict__ offs, const int* __restrict__ bsum,
                         int* __restrict__ cursor, int N) {
    int i = blockIdx.x * 256 + threadIdx.x;
    if (i >= N) return;
    int o = offs[i] + bsum[blockIdx.x];
    offs[i] = o;
    cursor[i] = o;
}

// ---- scatter edges into CSR order: pedge[slot] = {src, packed degs} ----
__global__ void k_scatter(const int* __restrict__ src, const int* __restrict__ dst,
                          const float* __restrict__ degrees,
                          int* __restrict__ cursor, uint2* __restrict__ pedge, int E) {
    int e = blockIdx.x * blockDim.x + threadIdx.x;
    if (e >= E) return;
    int d = dst[e];
    int slot = atomicAdd(&cursor[d], 1);
    unsigned pk = 0;
#pragma unroll
    for (int i = 0; i < 6; ++i) {
        float df = degrees[(size_t)e * 6 + i];
        pk |= ((unsigned)df) << (4 * i);
    }
    pedge[slot] = make_uint2((unsigned)src[e], pk);
}

// ---- aggregate: R11 structure; permuted column ownership in epilogue ----
__global__ void __launch_bounds__(256) k_aggregate(
    const char* __restrict__ PG,
    const int* __restrict__ row_start, const int* __restrict__ counts,
    const uint2* __restrict__ pedge,
    const float* __restrict__ norm, const float* __restrict__ W_edge,
    const float* __restrict__ bias, float* __restrict__ out, int N)
{
    __shared__ unsigned EL[4][192];
    const int wid = threadIdx.x >> 6;
    const int n = blockIdx.x * 4 + wid;
    if (n >= N) return;
    const int lane = threadIdx.x & 63;
    const int l2 = lane * 2;
    unsigned* el = EL[wid];

    // permuted column ownership (matches fp8/self pack): lane owns cols cA, cB=cA+16
    const int cA = (lane >> 5) * 64 + (lane & 1) * 32 + ((lane >> 1) & 15);
    const int cB = cA + 16;

    float wA[6], wB[6];
#pragma unroll
    for (int i = 0; i < 6; ++i) {
        wA[i] = W_edge[i * OUT_F + cA];
        wB[i] = W_edge[i * OUT_F + cB];
    }

    const int beg = row_start[n];
    const int end = beg + counts[n];

    float Swd[6] = {0.f, 0.f, 0.f, 0.f, 0.f, 0.f};
    float g0 = 0.f, g1 = 0.f;

    for (int p0 = beg; p0 < end; p0 += 64) {
        // ---- phase A: lane t handles edge p0+t ----
        const int t = p0 + lane;
        uint2 pe = (t < end) ? pedge[t] : make_uint2(0u, 0u);
        const unsigned dp = pe.y;
        const float nr = (dp != 0u) ? norm[pe.x] : 0.f;

        unsigned zm = 0;
#pragma unroll
        for (int i = 0; i < 6; ++i) {
            int d = (dp >> (4 * i)) & 15;
            if (d == 0) zm |= (1u << i);
            Swd[i] += nr * (float)d;
        }
        const int z = __popc(zm);
        const int ne = (dp == 0u) ? 0 : ((z <= 2) ? (1 + z) : (6 - z));

        int x = ne;
#pragma unroll
        for (int st = 1; st < 64; st <<= 1) {
            int v = __shfl_up(x, st);
            if (lane >= st) x += v;
        }
        const int excl = x - ne;
        const int total = __shfl(x, 63);

        if (ne) {
            const unsigned base = pe.x * (unsigned)PROWB;   // byte offset of P row
            int wp = excl;
            if (z <= 2) {
                el[wp++] = base + 768u;                     // + sum-slice (fp8)
#pragma unroll
                for (int i = 0; i < 6; ++i)
                    if ((zm >> i) & 1u) el[wp++] = (base + i * 128u) | 0x80000000u;  // - zero slices
            } else {
#pragma unroll
                for (int i = 0; i < 6; ++i)
                    if (!((zm >> i) & 1u)) el[wp++] = base + i * 128u;               // + nonzero slices
            }
        }
        asm volatile("s_waitcnt lgkmcnt(0)" ::: "memory");

        // ---- phase B: wave-uniform entries -> SGPR base, ushort gather + fp8 decode ----
        int j = 0;
        for (; j + 8 <= total; j += 8) {
            unsigned ev[8];
            unsigned short qv[8];
#pragma unroll
            for (int q = 0; q < 8; ++q)
                ev[q] = __builtin_amdgcn_readfirstlane(el[j + q]);
#pragma unroll
            for (int q = 0; q < 8; ++q)
                qv[q] = *(const unsigned short*)(PG + (ev[q] & 0x7fffffffu) + l2);
#pragma unroll
            for (int q = 0; q < 8; ++q) {
                f32x2 fq = __builtin_amdgcn_cvt_pk_f32_fp8((int)qv[q], false);
                float sg = __uint_as_float(0x3f800000u | (ev[q] & 0x80000000u));
                g0 = fmaf(sg, fq.x, g0);
                g1 = fmaf(sg, fq.y, g1);
            }
        }
        for (; j < total; ++j) {
            unsigned e0 = __builtin_amdgcn_readfirstlane(el[j]);
            unsigned short q0 = *(const unsigned short*)(PG + (e0 & 0x7fffffffu) + l2);
            f32x2 f0 = __builtin_amdgcn_cvt_pk_f32_fp8((int)q0, false);
            float sg = __uint_as_float(0x3f800000u | (e0 & 0x80000000u));
            g0 = fmaf(sg, f0.x, g0);
            g1 = fmaf(sg, f0.y, g1);
        }
    }

    // ---- reduce Swd across the wave, fold base term (permuted cols) ----
    float b0 = 0.f, b1 = 0.f;
#pragma unroll
    for (int i = 0; i < 6; ++i) {
        float v = Swd[i];
#pragma unroll
        for (int st = 1; st < 64; st <<= 1) v += __shfl_xor(v, st);
        b0 = fmaf(v, wA[i], b0);
        b1 = fmaf(v, wB[i], b1);
    }

    // ---- fused epilogue: relu(accum*norm + self + bias) at permuted cols ----
    const unsigned us = *(const unsigned*)(PG + (size_t)n * PROWB + 896 + lane * 4);
    const float nd = norm[n];
    float o0 = fmaxf((g0 + b0) * nd + bf_lo(us) + bias[cA], 0.f);
    float o1 = fmaxf((g1 + b1) * nd + bf_hi(us) + bias[cB], 0.f);
    out[(size_t)n * OUT_F + cA] = o0;
    out[(size_t)n * OUT_F + cB] = o1;
}

extern "C" void kernel_launch(void* const* d_in, const int* in_sizes, int n_in,
                              void* d_out, int out_size, void* d_ws, size_t ws_size,
                              hipStream_t stream)
{
    const float* h       = (const float*)d_in[0];
    const float* degrees = (const float*)d_in[1];
    const float* norm    = (const float*)d_in[2];
    const int*   src     = (const int*)d_in[3];
    const int*   dst     = (const int*)d_in[4];
    const float* W_self  = (const float*)d_in[5];
    const float* b_self  = (const float*)d_in[6];
    const float* W_node  = (const float*)d_in[7];
    const float* b_node  = (const float*)d_in[8];
    const float* W_edge  = (const float*)d_in[9];
    const float* bias    = (const float*)d_in[10];
    float* out = (float*)d_out;

    const int N = in_sizes[2];   // norm [N,1]
    const int E = in_sizes[3];   // src [E]
    const int NB = (N + 255) / 256;

    char* ws = (char*)d_ws;
    size_t off = 0;
    auto alloc = [&](size_t sz) { size_t o = off; off = (off + sz + 255) & ~(size_t)255; return o; };
    char*           PG     = (char*)(ws + alloc((size_t)N * PROWB));               // 57.6 MB
    unsigned short* hb     = (unsigned short*)(ws + alloc((size_t)N * IN_F * 2));  // 25.6 MB
    unsigned short* Wt     = (unsigned short*)(ws + alloc((size_t)NCOLS * IN_F * 2));
    float*          bvec   = (float*)(ws + alloc(NCOLS * 4));
    int*            counts = (int*)(ws + alloc((size_t)N * 4));
    int*            offs   = (int*)(ws + alloc((size_t)N * 4));
    int*            cursor = (int*)(ws + alloc((size_t)N * 4));
    int*            bsum   = (int*)(ws + alloc((size_t)NB * 4));
    uint2*          pedge  = (uint2*)(ws + alloc((size_t)E * 8));                  // 6.4 MB

    hipMemsetAsync(counts, 0, (size_t)N * 4, stream);

    int t8 = N * (IN_F / 8);
    k_conv_h<<<(t8 + 255) / 256, 256, 0, stream>>>(h, hb, t8);

    int tw = IN_F * NCOLS;
    k_conv_w<<<(tw + 255) / 256, 256, 0, stream>>>(W_node, W_self, b_node, b_self, Wt, bvec, tw);

    const int R  = (N + BM - 1) / BM;
    const int RP = (R + 7) / 8;
    k_gemm<<<RP * 8 * 8, 256, 0, stream>>>(hb, Wt, bvec, norm, PG, N, RP);

    k_hist<<<(E + 255) / 256, 256, 0, stream>>>(dst, counts, E);
    k_scan_a<<<NB, 256, 0, stream>>>(counts, offs, bsum, N);
    k_scan_b<<<1, 256, 0, stream>>>(bsum, NB);
    k_scan_c<<<NB, 256, 0, stream>>>(offs, bsum, cursor, N);
    k_scatter<<<(E + 255) / 256, 256, 0, stream>>>(src, dst, degrees, cursor, pedge, E);

    k_aggregate<<<(N + 3) / 4, 256, 0, stream>>>(PG, offs, counts, pedge,
                                                 norm, W_edge, bias, out, N);
}

// Round 13
// 207.668 us; speedup vs baseline: 1.0149x; 1.0149x over previous
//
#include <hip/hip_runtime.h>
#include <stdint.h>

#define IN_F 256
#define OUT_F 128
#define NCOLS 1024   // GEMM cols: 768 slices + 128 sum-slice + 128 self
#define PROWB 1152   // P row bytes: 896 fp8 (slices+sum) + 256 bf16 self
#define BM 64
#define BN 128
#define BK 32

using bf16x8 = __attribute__((ext_vector_type(8))) __bf16;
using f32x4  = __attribute__((ext_vector_type(4))) float;
using f32x2  = __attribute__((ext_vector_type(2))) float;

static __device__ __forceinline__ unsigned short f2bf(float f) {
    unsigned u = __float_as_uint(f);
    u = u + 0x7fffu + ((u >> 16) & 1u);   // RNE
    return (unsigned short)(u >> 16);
}
static __device__ __forceinline__ float bf_lo(unsigned u) { return __uint_as_float(u << 16); }
static __device__ __forceinline__ float bf_hi(unsigned u) { return __uint_as_float(u & 0xffff0000u); }

static __device__ __forceinline__ void async_load16(const void* g, void* l) {
    __builtin_amdgcn_global_load_lds(
        (__attribute__((address_space(1))) void*)g,
        (__attribute__((address_space(3))) void*)l,
        16, 0, 0);
}

// ---- Wt[1024][256] = [W_node | sum(slices) | W_self]^T bf16; bvec[1024] ----
__global__ void k_conv_w(const float* __restrict__ Wn, const float* __restrict__ Ws,
                         const float* __restrict__ bn, const float* __restrict__ bs,
                         unsigned short* __restrict__ Wt, float* __restrict__ bvec, int total) {
    int i = blockIdx.x * blockDim.x + threadIdx.x;   // i = k*1024 + c
    if (i >= total) return;
    int k = i >> 10, c = i & 1023;
    float v;
    if (c < 768) {
        v = Wn[(size_t)k * 768 + c];
    } else if (c < 896) {
        int j = c - 768; v = 0.f;
#pragma unroll
        for (int s = 0; s < 6; ++s) v += Wn[(size_t)k * 768 + s * 128 + j];
    } else {
        v = Ws[(size_t)k * 128 + (c - 896)];
    }
    Wt[(size_t)c * IN_F + k] = f2bf(v);

    if (i < NCOLS) {
        float b;
        if (i < 768) b = bn[i];
        else if (i < 896) {
            int j = i - 768; b = 0.f;
#pragma unroll
            for (int s = 0; s < 6; ++s) b += bn[s * 128 + j];
        } else b = bs[i - 896];
        bvec[i] = b;
    }
}

// ---- GEMM: fused f32->bf16 A-staging; direct permuted fp8/bf16 stores ----
__global__ void __launch_bounds__(256) k_gemm(
    const float* __restrict__ h,                 // [N,256] f32 (raw input)
    const unsigned short* __restrict__ Wt,
    const float* __restrict__ bvec,
    const float* __restrict__ norm,
    char* __restrict__ PG, int N, int rowsPerXcd)
{
    __shared__ char lds[(BM + BN) * BK * 2];       // 12 KB (A 4 KB, B 8 KB)
    char* Ab = lds;
    char* Bb = lds + BM * BK * 2;

    const int f  = blockIdx.x;
    const int xc = f & 7;
    const int j  = f >> 3;
    const int rs = xc * rowsPerXcd + (j >> 3);
    const int ct = j & 7;
    const int r0 = rs * BM;
    if (r0 >= N) return;
    const int c0 = ct * BN;

    const int tid = threadIdx.x;
    const int wid = tid >> 6, lane = tid & 63;
    const int lrow = lane & 15, s = lane >> 4;
    const int wr = wid >> 1, wc = wid & 1;

    const int arow = tid >> 2;
    const int achunk = (tid & 3) ^ ((arow >> 1) & 3);
    int agrow = r0 + arow; if (agrow >= N) agrow = N - 1;
    const float* aseg = h + (size_t)agrow * IN_F + achunk * 8;   // 8 f32 per chunk

    const int bcol0 = tid >> 2;
    const int bchunk0 = (tid & 3) ^ ((bcol0 >> 1) & 3);
    const unsigned short* bseg0 = Wt + (size_t)(c0 + bcol0) * IN_F + bchunk0 * 8;
    const int idx1 = tid + 256;
    const int bcol1 = idx1 >> 2;
    const int bchunk1 = (idx1 & 3) ^ ((bcol1 >> 1) & 3);
    const unsigned short* bseg1 = Wt + (size_t)(c0 + bcol1) * IN_F + bchunk1 * 8;

    int a_off[2], b_off[4];
#pragma unroll
    for (int m = 0; m < 2; ++m) {
        int rl = wr * 32 + m * 16 + lrow;
        a_off[m] = rl * 64 + ((s ^ ((rl >> 1) & 3)) << 4);
    }
#pragma unroll
    for (int n = 0; n < 4; ++n) {
        int cl = wc * 64 + n * 16 + lrow;
        b_off[n] = cl * 64 + ((s ^ ((cl >> 1) & 3)) << 4);
    }

    float nrmv[2][4];
#pragma unroll
    for (int m = 0; m < 2; ++m)
#pragma unroll
        for (int r = 0; r < 4; ++r) {
            int rg = r0 + wr * 32 + m * 16 + s * 4 + r;
            nrmv[m][r] = norm[rg < N ? rg : N - 1];
        }

    f32x4 acc[2][4] = {};

    for (int kk = 0; kk < IN_F / BK; ++kk) {
        // A: reg-staged f32 -> bf16 (fused conversion; same source swizzle pattern)
        float4 a0 = *(const float4*)(aseg + kk * BK);
        float4 a1 = *(const float4*)(aseg + kk * BK + 4);
        // B: async direct-to-LDS
        async_load16(bseg0 + kk * BK, Bb + tid * 16);
        async_load16(bseg1 + kk * BK, Bb + (tid + 256) * 16);
        union { unsigned short us[8]; uint4 v; } u;
        u.us[0] = f2bf(a0.x); u.us[1] = f2bf(a0.y); u.us[2] = f2bf(a0.z); u.us[3] = f2bf(a0.w);
        u.us[4] = f2bf(a1.x); u.us[5] = f2bf(a1.y); u.us[6] = f2bf(a1.z); u.us[7] = f2bf(a1.w);
        *(uint4*)(Ab + tid * 16) = u.v;
        __syncthreads();

        bf16x8 af[2], bfv[4];
#pragma unroll
        for (int m = 0; m < 2; ++m) af[m] = *(const bf16x8*)(Ab + a_off[m]);
#pragma unroll
        for (int n = 0; n < 4; ++n) bfv[n] = *(const bf16x8*)(Bb + b_off[n]);
#pragma unroll
        for (int m = 0; m < 2; ++m)
#pragma unroll
            for (int n = 0; n < 4; ++n)
                acc[m][n] = __builtin_amdgcn_mfma_f32_16x16x32_bf16(af[m], bfv[n], acc[m][n], 0, 0, 0);
        __syncthreads();
    }

    float bvn[4];
#pragma unroll
    for (int n = 0; n < 4; ++n) bvn[n] = bvec[c0 + wc * 64 + n * 16 + lrow];

    if (ct < 7) {
        // fp8 tile in packed fragment order: dword d = wc*16+lrow, byte b -> col (d>>4)*64+b*16+(d&15)
#pragma unroll
        for (int m = 0; m < 2; ++m) {
#pragma unroll
            for (int r = 0; r < 4; ++r) {
                const int rg = r0 + wr * 32 + m * 16 + s * 4 + r;
                if (rg >= N) continue;
                const float sc = nrmv[m][r];
                float v0 = (acc[m][0][r] + bvn[0]) * sc;
                float v1 = (acc[m][1][r] + bvn[1]) * sc;
                float v2 = (acc[m][2][r] + bvn[2]) * sc;
                float v3 = (acc[m][3][r] + bvn[3]) * sc;
                int pk = __builtin_amdgcn_cvt_pk_fp8_f32(v0, v1, 0, false);
                pk = __builtin_amdgcn_cvt_pk_fp8_f32(v2, v3, pk, true);
                *(int*)(PG + (size_t)rg * PROWB + ct * 128 + (wc * 16 + lrow) * 4) = pk;
            }
        }
    } else {
        // bf16 self tile, permuted: dword L=wc*32+2*lrow holds cols (cA(L), cA(L)+16)
#pragma unroll
        for (int m = 0; m < 2; ++m) {
#pragma unroll
            for (int r = 0; r < 4; ++r) {
                const int rg = r0 + wr * 32 + m * 16 + s * 4 + r;
                if (rg >= N) continue;
                float v0 = acc[m][0][r] + bvn[0];
                float v1 = acc[m][1][r] + bvn[1];
                float v2 = acc[m][2][r] + bvn[2];
                float v3 = acc[m][3][r] + bvn[3];
                uint2 dd;
                dd.x = (unsigned)f2bf(v0) | ((unsigned)f2bf(v1) << 16);
                dd.y = (unsigned)f2bf(v2) | ((unsigned)f2bf(v3) << 16);
                *(uint2*)(PG + (size_t)rg * PROWB + 896 + (wc * 32 + 2 * lrow) * 4) = dd;
            }
        }
    }
}

// ---- histogram over dst (edge counts) ----
__global__ void k_hist(const int* __restrict__ dst, int* __restrict__ counts, int E) {
    int e = blockIdx.x * blockDim.x + threadIdx.x;
    if (e < E) atomicAdd(&counts[dst[e]], 1);
}

// ---- 3-phase exclusive scan over counts[N] ----
__global__ void __launch_bounds__(256) k_scan_a(const int* __restrict__ counts,
                                                int* __restrict__ offs,
                                                int* __restrict__ bsum, int N) {
    __shared__ int sm[256];
    int tid = threadIdx.x;
    int i = blockIdx.x * 256 + tid;
    int v = (i < N) ? counts[i] : 0;
    sm[tid] = v;
    __syncthreads();
#pragma unroll
    for (int st = 1; st < 256; st <<= 1) {
        int t = (tid >= st) ? sm[tid - st] : 0;
        __syncthreads();
        sm[tid] += t;
        __syncthreads();
    }
    if (i < N) offs[i] = sm[tid] - v;
    if (tid == 255) bsum[blockIdx.x] = sm[255];
}

__global__ void __launch_bounds__(256) k_scan_b(int* __restrict__ bsum, int NB) {
    __shared__ int sm[256];
    int tid = threadIdx.x;
    int v = (tid < NB) ? bsum[tid] : 0;
    sm[tid] = v;
    __syncthreads();
#pragma unroll
    for (int st = 1; st < 256; st <<= 1) {
        int t = (tid >= st) ? sm[tid - st] : 0;
        __syncthreads();
        sm[tid] += t;
        __syncthreads();
    }
    if (tid < NB) bsum[tid] = sm[tid] - v;
}

__global__ void k_scan_c(int* __restrict__ offs, const int* __restrict__ bsum,
                         int* __restrict__ cursor, int N) {
    int i = blockIdx.x * 256 + threadIdx.x;
    if (i >= N) return;
    int o = offs[i] + bsum[blockIdx.x];
    offs[i] = o;
    cursor[i] = o;
}

// ---- scatter edges into CSR order: pedge[slot] = {src, packed degs} ----
__global__ void k_scatter(const int* __restrict__ src, const int* __restrict__ dst,
                          const float* __restrict__ degrees,
                          int* __restrict__ cursor, uint2* __restrict__ pedge, int E) {
    int e = blockIdx.x * blockDim.x + threadIdx.x;
    if (e >= E) return;
    int d = dst[e];
    int slot = atomicAdd(&cursor[d], 1);
    unsigned pk = 0;
#pragma unroll
    for (int i = 0; i < 6; ++i) {
        float df = degrees[(size_t)e * 6 + i];
        pk |= ((unsigned)df) << (4 * i);
    }
    pedge[slot] = make_uint2((unsigned)src[e], pk);
}

// ---- aggregate: R12 kernel (unchanged) ----
__global__ void __launch_bounds__(256) k_aggregate(
    const char* __restrict__ PG,
    const int* __restrict__ row_start, const int* __restrict__ counts,
    const uint2* __restrict__ pedge,
    const float* __restrict__ norm, const float* __restrict__ W_edge,
    const float* __restrict__ bias, float* __restrict__ out, int N)
{
    __shared__ unsigned EL[4][192];
    const int wid = threadIdx.x >> 6;
    const int n = blockIdx.x * 4 + wid;
    if (n >= N) return;
    const int lane = threadIdx.x & 63;
    const int l2 = lane * 2;
    unsigned* el = EL[wid];

    // permuted column ownership (matches fp8/self pack): lane owns cols cA, cB=cA+16
    const int cA = (lane >> 5) * 64 + (lane & 1) * 32 + ((lane >> 1) & 15);
    const int cB = cA + 16;

    float wA[6], wB[6];
#pragma unroll
    for (int i = 0; i < 6; ++i) {
        wA[i] = W_edge[i * OUT_F + cA];
        wB[i] = W_edge[i * OUT_F + cB];
    }

    const int beg = row_start[n];
    const int end = beg + counts[n];

    float Swd[6] = {0.f, 0.f, 0.f, 0.f, 0.f, 0.f};
    float g0 = 0.f, g1 = 0.f;

    for (int p0 = beg; p0 < end; p0 += 64) {
        const int t = p0 + lane;
        uint2 pe = (t < end) ? pedge[t] : make_uint2(0u, 0u);
        const unsigned dp = pe.y;
        const float nr = (dp != 0u) ? norm[pe.x] : 0.f;

        unsigned zm = 0;
#pragma unroll
        for (int i = 0; i < 6; ++i) {
            int d = (dp >> (4 * i)) & 15;
            if (d == 0) zm |= (1u << i);
            Swd[i] += nr * (float)d;
        }
        const int z = __popc(zm);
        const int ne = (dp == 0u) ? 0 : ((z <= 2) ? (1 + z) : (6 - z));

        int x = ne;
#pragma unroll
        for (int st = 1; st < 64; st <<= 1) {
            int v = __shfl_up(x, st);
            if (lane >= st) x += v;
        }
        const int excl = x - ne;
        const int total = __shfl(x, 63);

        if (ne) {
            const unsigned base = pe.x * (unsigned)PROWB;   // byte offset of P row
            int wp = excl;
            if (z <= 2) {
                el[wp++] = base + 768u;                     // + sum-slice (fp8)
#pragma unroll
                for (int i = 0; i < 6; ++i)
                    if ((zm >> i) & 1u) el[wp++] = (base + i * 128u) | 0x80000000u;  // - zero slices
            } else {
#pragma unroll
                for (int i = 0; i < 6; ++i)
                    if (!((zm >> i) & 1u)) el[wp++] = base + i * 128u;               // + nonzero slices
            }
        }
        asm volatile("s_waitcnt lgkmcnt(0)" ::: "memory");

        int j = 0;
        for (; j + 8 <= total; j += 8) {
            unsigned ev[8];
            unsigned short qv[8];
#pragma unroll
            for (int q = 0; q < 8; ++q)
                ev[q] = __builtin_amdgcn_readfirstlane(el[j + q]);
#pragma unroll
            for (int q = 0; q < 8; ++q)
                qv[q] = *(const unsigned short*)(PG + (ev[q] & 0x7fffffffu) + l2);
#pragma unroll
            for (int q = 0; q < 8; ++q) {
                f32x2 fq = __builtin_amdgcn_cvt_pk_f32_fp8((int)qv[q], false);
                float sg = __uint_as_float(0x3f800000u | (ev[q] & 0x80000000u));
                g0 = fmaf(sg, fq.x, g0);
                g1 = fmaf(sg, fq.y, g1);
            }
        }
        for (; j < total; ++j) {
            unsigned e0 = __builtin_amdgcn_readfirstlane(el[j]);
            unsigned short q0 = *(const unsigned short*)(PG + (e0 & 0x7fffffffu) + l2);
            f32x2 f0 = __builtin_amdgcn_cvt_pk_f32_fp8((int)q0, false);
            float sg = __uint_as_float(0x3f800000u | (e0 & 0x80000000u));
            g0 = fmaf(sg, f0.x, g0);
            g1 = fmaf(sg, f0.y, g1);
        }
    }

    float b0 = 0.f, b1 = 0.f;
#pragma unroll
    for (int i = 0; i < 6; ++i) {
        float v = Swd[i];
#pragma unroll
        for (int st = 1; st < 64; st <<= 1) v += __shfl_xor(v, st);
        b0 = fmaf(v, wA[i], b0);
        b1 = fmaf(v, wB[i], b1);
    }

    const unsigned us = *(const unsigned*)(PG + (size_t)n * PROWB + 896 + lane * 4);
    const float nd = norm[n];
    float o0 = fmaxf((g0 + b0) * nd + bf_lo(us) + bias[cA], 0.f);
    float o1 = fmaxf((g1 + b1) * nd + bf_hi(us) + bias[cB], 0.f);
    out[(size_t)n * OUT_F + cA] = o0;
    out[(size_t)n * OUT_F + cB] = o1;
}

extern "C" void kernel_launch(void* const* d_in, const int* in_sizes, int n_in,
                              void* d_out, int out_size, void* d_ws, size_t ws_size,
                              hipStream_t stream)
{
    const float* h       = (const float*)d_in[0];
    const float* degrees = (const float*)d_in[1];
    const float* norm    = (const float*)d_in[2];
    const int*   src     = (const int*)d_in[3];
    const int*   dst     = (const int*)d_in[4];
    const float* W_self  = (const float*)d_in[5];
    const float* b_self  = (const float*)d_in[6];
    const float* W_node  = (const float*)d_in[7];
    const float* b_node  = (const float*)d_in[8];
    const float* W_edge  = (const float*)d_in[9];
    const float* bias    = (const float*)d_in[10];
    float* out = (float*)d_out;

    const int N = in_sizes[2];   // norm [N,1]
    const int E = in_sizes[3];   // src [E]
    const int NB = (N + 255) / 256;

    char* ws = (char*)d_ws;
    size_t off = 0;
    auto alloc = [&](size_t sz) { size_t o = off; off = (off + sz + 255) & ~(size_t)255; return o; };
    char*           PG     = (char*)(ws + alloc((size_t)N * PROWB));               // 57.6 MB
    unsigned short* Wt     = (unsigned short*)(ws + alloc((size_t)NCOLS * IN_F * 2));
    float*          bvec   = (float*)(ws + alloc(NCOLS * 4));
    int*            counts = (int*)(ws + alloc((size_t)N * 4));
    int*            offs   = (int*)(ws + alloc((size_t)N * 4));
    int*            cursor = (int*)(ws + alloc((size_t)N * 4));
    int*            bsum   = (int*)(ws + alloc((size_t)NB * 4));
    uint2*          pedge  = (uint2*)(ws + alloc((size_t)E * 8));                  // 6.4 MB

    hipMemsetAsync(counts, 0, (size_t)N * 4, stream);

    int tw = IN_F * NCOLS;
    k_conv_w<<<(tw + 255) / 256, 256, 0, stream>>>(W_node, W_self, b_node, b_self, Wt, bvec, tw);

    const int R  = (N + BM - 1) / BM;
    const int RP = (R + 7) / 8;
    k_gemm<<<RP * 8 * 8, 256, 0, stream>>>(h, Wt, bvec, norm, PG, N, RP);

    k_hist<<<(E + 255) / 256, 256, 0, stream>>>(dst, counts, E);
    k_scan_a<<<NB, 256, 0, stream>>>(counts, offs, bsum, N);
    k_scan_b<<<1, 256, 0, stream>>>(bsum, NB);
    k_scan_c<<<NB, 256, 0, stream>>>(offs, bsum, cursor, N);
    k_scatter<<<(E + 255) / 256, 256, 0, stream>>>(src, dst, degrees, cursor, pedge, E);

    k_aggregate<<<(N + 3) / 4, 256, 0, stream>>>(PG, offs, counts, pedge,
                                                 norm, W_edge, bias, out, N);
}

// Round 14
// 202.210 us; speedup vs baseline: 1.0423x; 1.0270x over previous
//
#include <hip/hip_runtime.h>
#include <stdint.h>

#define IN_F 256
#define OUT_F 128
#define NCOLS 1024   // GEMM cols: 768 slices + 128 sum-slice + 128 self
#define PROWB 1152   // P row bytes: 896 fp8 (slices+sum) + 256 bf16 self
#define BM 64
#define BN 128
#define BK 32

using bf16x8 = __attribute__((ext_vector_type(8))) __bf16;
using f32x4  = __attribute__((ext_vector_type(4))) float;
using f32x2  = __attribute__((ext_vector_type(2))) float;

static __device__ __forceinline__ unsigned short f2bf(float f) {
    unsigned u = __float_as_uint(f);
    u = u + 0x7fffu + ((u >> 16) & 1u);   // RNE
    return (unsigned short)(u >> 16);
}
static __device__ __forceinline__ float bf_lo(unsigned u) { return __uint_as_float(u << 16); }
static __device__ __forceinline__ float bf_hi(unsigned u) { return __uint_as_float(u & 0xffff0000u); }

static __device__ __forceinline__ void async_load16(const void* g, void* l) {
    __builtin_amdgcn_global_load_lds(
        (__attribute__((address_space(1))) void*)g,
        (__attribute__((address_space(3))) void*)l,
        16, 0, 0);
}

// ---- fused prep: h->bf16, Wt build, dst histogram (3 independent jobs, 1 launch) ----
__global__ void k_prep(const float* __restrict__ h, unsigned short* __restrict__ hb, int total8,
                       const float* __restrict__ Wn, const float* __restrict__ Ws,
                       const float* __restrict__ bn, const float* __restrict__ bs,
                       unsigned short* __restrict__ Wt, float* __restrict__ bvec, int totalw,
                       const int* __restrict__ dst, int* __restrict__ counts, int E) {
    int i = blockIdx.x * blockDim.x + threadIdx.x;

    if (i < total8) {   // conv_h: 8 f32 -> 8 bf16
        const float4* src = ((const float4*)h) + (size_t)i * 2;
        float4 a = src[0], b = src[1];
        union { unsigned short us[8]; uint4 v; } u;
        u.us[0] = f2bf(a.x); u.us[1] = f2bf(a.y); u.us[2] = f2bf(a.z); u.us[3] = f2bf(a.w);
        u.us[4] = f2bf(b.x); u.us[5] = f2bf(b.y); u.us[6] = f2bf(b.z); u.us[7] = f2bf(b.w);
        ((uint4*)hb)[i] = u.v;
    }

    if (i < totalw) {   // conv_w: Wt[1024][256] = [W_node | sum | W_self]^T
        int k = i >> 10, c = i & 1023;
        float v;
        if (c < 768) {
            v = Wn[(size_t)k * 768 + c];
        } else if (c < 896) {
            int j = c - 768; v = 0.f;
#pragma unroll
            for (int s = 0; s < 6; ++s) v += Wn[(size_t)k * 768 + s * 128 + j];
        } else {
            v = Ws[(size_t)k * 128 + (c - 896)];
        }
        Wt[(size_t)c * IN_F + k] = f2bf(v);

        if (i < NCOLS) {
            float b;
            if (i < 768) b = bn[i];
            else if (i < 896) {
                int j = i - 768; b = 0.f;
#pragma unroll
                for (int s = 0; s < 6; ++s) b += bn[s * 128 + j];
            } else b = bs[i - 896];
            bvec[i] = b;
        }
    }

    if (i < E) atomicAdd(&counts[dst[i]], 1);   // hist
}

// ---- GEMM (R12-proven): async hb staging + direct permuted fp8/bf16 stores ----
__global__ void __launch_bounds__(256) k_gemm(
    const unsigned short* __restrict__ hb,
    const unsigned short* __restrict__ Wt,
    const float* __restrict__ bvec,
    const float* __restrict__ norm,
    char* __restrict__ PG, int N, int rowsPerXcd)
{
    __shared__ char lds[(BM + BN) * BK * 2];       // 12 KB (A 4 KB, B 8 KB)
    char* Ab = lds;
    char* Bb = lds + BM * BK * 2;

    const int f  = blockIdx.x;
    const int xc = f & 7;
    const int j  = f >> 3;
    const int rs = xc * rowsPerXcd + (j >> 3);
    const int ct = j & 7;
    const int r0 = rs * BM;
    if (r0 >= N) return;
    const int c0 = ct * BN;

    const int tid = threadIdx.x;
    const int wid = tid >> 6, lane = tid & 63;
    const int lrow = lane & 15, s = lane >> 4;
    const int wr = wid >> 1, wc = wid & 1;

    const int arow = tid >> 2;
    const int achunk = (tid & 3) ^ ((arow >> 1) & 3);
    int agrow = r0 + arow; if (agrow >= N) agrow = N - 1;
    const unsigned short* aseg = hb + (size_t)agrow * IN_F + achunk * 8;

    const int bcol0 = tid >> 2;
    const int bchunk0 = (tid & 3) ^ ((bcol0 >> 1) & 3);
    const unsigned short* bseg0 = Wt + (size_t)(c0 + bcol0) * IN_F + bchunk0 * 8;
    const int idx1 = tid + 256;
    const int bcol1 = idx1 >> 2;
    const int bchunk1 = (idx1 & 3) ^ ((bcol1 >> 1) & 3);
    const unsigned short* bseg1 = Wt + (size_t)(c0 + bcol1) * IN_F + bchunk1 * 8;

    int a_off[2], b_off[4];
#pragma unroll
    for (int m = 0; m < 2; ++m) {
        int rl = wr * 32 + m * 16 + lrow;
        a_off[m] = rl * 64 + ((s ^ ((rl >> 1) & 3)) << 4);
    }
#pragma unroll
    for (int n = 0; n < 4; ++n) {
        int cl = wc * 64 + n * 16 + lrow;
        b_off[n] = cl * 64 + ((s ^ ((cl >> 1) & 3)) << 4);
    }

    float nrmv[2][4];
#pragma unroll
    for (int m = 0; m < 2; ++m)
#pragma unroll
        for (int r = 0; r < 4; ++r) {
            int rg = r0 + wr * 32 + m * 16 + s * 4 + r;
            nrmv[m][r] = norm[rg < N ? rg : N - 1];
        }

    f32x4 acc[2][4] = {};

    for (int kk = 0; kk < IN_F / BK; ++kk) {
        async_load16(aseg + kk * BK, Ab + tid * 16);
        async_load16(bseg0 + kk * BK, Bb + tid * 16);
        async_load16(bseg1 + kk * BK, Bb + (tid + 256) * 16);
        __syncthreads();

        bf16x8 af[2], bfv[4];
#pragma unroll
        for (int m = 0; m < 2; ++m) af[m] = *(const bf16x8*)(Ab + a_off[m]);
#pragma unroll
        for (int n = 0; n < 4; ++n) bfv[n] = *(const bf16x8*)(Bb + b_off[n]);
#pragma unroll
        for (int m = 0; m < 2; ++m)
#pragma unroll
            for (int n = 0; n < 4; ++n)
                acc[m][n] = __builtin_amdgcn_mfma_f32_16x16x32_bf16(af[m], bfv[n], acc[m][n], 0, 0, 0);
        __syncthreads();
    }

    float bvn[4];
#pragma unroll
    for (int n = 0; n < 4; ++n) bvn[n] = bvec[c0 + wc * 64 + n * 16 + lrow];

    if (ct < 7) {
        // fp8 tile in packed fragment order: dword d = wc*16+lrow, byte b -> col (d>>4)*64+b*16+(d&15)
#pragma unroll
        for (int m = 0; m < 2; ++m) {
#pragma unroll
            for (int r = 0; r < 4; ++r) {
                const int rg = r0 + wr * 32 + m * 16 + s * 4 + r;
                if (rg >= N) continue;
                const float sc = nrmv[m][r];
                float v0 = (acc[m][0][r] + bvn[0]) * sc;
                float v1 = (acc[m][1][r] + bvn[1]) * sc;
                float v2 = (acc[m][2][r] + bvn[2]) * sc;
                float v3 = (acc[m][3][r] + bvn[3]) * sc;
                int pk = __builtin_amdgcn_cvt_pk_fp8_f32(v0, v1, 0, false);
                pk = __builtin_amdgcn_cvt_pk_fp8_f32(v2, v3, pk, true);
                *(int*)(PG + (size_t)rg * PROWB + ct * 128 + (wc * 16 + lrow) * 4) = pk;
            }
        }
    } else {
        // bf16 self tile, permuted: dword L=wc*32+2*lrow holds cols (cA(L), cA(L)+16)
#pragma unroll
        for (int m = 0; m < 2; ++m) {
#pragma unroll
            for (int r = 0; r < 4; ++r) {
                const int rg = r0 + wr * 32 + m * 16 + s * 4 + r;
                if (rg >= N) continue;
                float v0 = acc[m][0][r] + bvn[0];
                float v1 = acc[m][1][r] + bvn[1];
                float v2 = acc[m][2][r] + bvn[2];
                float v3 = acc[m][3][r] + bvn[3];
                uint2 dd;
                dd.x = (unsigned)f2bf(v0) | ((unsigned)f2bf(v1) << 16);
                dd.y = (unsigned)f2bf(v2) | ((unsigned)f2bf(v3) << 16);
                *(uint2*)(PG + (size_t)rg * PROWB + 896 + (wc * 32 + 2 * lrow) * 4) = dd;
            }
        }
    }
}

// ---- 3-phase exclusive scan over counts[N] ----
__global__ void __launch_bounds__(256) k_scan_a(const int* __restrict__ counts,
                                                int* __restrict__ offs,
                                                int* __restrict__ bsum, int N) {
    __shared__ int sm[256];
    int tid = threadIdx.x;
    int i = blockIdx.x * 256 + tid;
    int v = (i < N) ? counts[i] : 0;
    sm[tid] = v;
    __syncthreads();
#pragma unroll
    for (int st = 1; st < 256; st <<= 1) {
        int t = (tid >= st) ? sm[tid - st] : 0;
        __syncthreads();
        sm[tid] += t;
        __syncthreads();
    }
    if (i < N) offs[i] = sm[tid] - v;
    if (tid == 255) bsum[blockIdx.x] = sm[255];
}

__global__ void __launch_bounds__(256) k_scan_b(int* __restrict__ bsum, int NB) {
    __shared__ int sm[256];
    int tid = threadIdx.x;
    int v = (tid < NB) ? bsum[tid] : 0;
    sm[tid] = v;
    __syncthreads();
#pragma unroll
    for (int st = 1; st < 256; st <<= 1) {
        int t = (tid >= st) ? sm[tid - st] : 0;
        __syncthreads();
        sm[tid] += t;
        __syncthreads();
    }
    if (tid < NB) bsum[tid] = sm[tid] - v;
}

__global__ void k_scan_c(int* __restrict__ offs, const int* __restrict__ bsum,
                         int* __restrict__ cursor, int N) {
    int i = blockIdx.x * 256 + threadIdx.x;
    if (i >= N) return;
    int o = offs[i] + bsum[blockIdx.x];
    offs[i] = o;
    cursor[i] = o;
}

// ---- scatter edges into CSR order: pedge[slot] = {src, packed degs} ----
__global__ void k_scatter(const int* __restrict__ src, const int* __restrict__ dst,
                          const float* __restrict__ degrees,
                          int* __restrict__ cursor, uint2* __restrict__ pedge, int E) {
    int e = blockIdx.x * blockDim.x + threadIdx.x;
    if (e >= E) return;
    int d = dst[e];
    int slot = atomicAdd(&cursor[d], 1);
    unsigned pk = 0;
#pragma unroll
    for (int i = 0; i < 6; ++i) {
        float df = degrees[(size_t)e * 6 + i];
        pk |= ((unsigned)df) << (4 * i);
    }
    pedge[slot] = make_uint2((unsigned)src[e], pk);
}

// ---- aggregate (R12-proven): worklist + SGPR-addressed fp8 gathers ----
__global__ void __launch_bounds__(256) k_aggregate(
    const char* __restrict__ PG,
    const int* __restrict__ row_start, const int* __restrict__ counts,
    const uint2* __restrict__ pedge,
    const float* __restrict__ norm, const float* __restrict__ W_edge,
    const float* __restrict__ bias, float* __restrict__ out, int N)
{
    __shared__ unsigned EL[4][192];
    const int wid = threadIdx.x >> 6;
    const int n = blockIdx.x * 4 + wid;
    if (n >= N) return;
    const int lane = threadIdx.x & 63;
    const int l2 = lane * 2;
    unsigned* el = EL[wid];

    // permuted column ownership (matches fp8/self pack): lane owns cols cA, cB=cA+16
    const int cA = (lane >> 5) * 64 + (lane & 1) * 32 + ((lane >> 1) & 15);
    const int cB = cA + 16;

    float wA[6], wB[6];
#pragma unroll
    for (int i = 0; i < 6; ++i) {
        wA[i] = W_edge[i * OUT_F + cA];
        wB[i] = W_edge[i * OUT_F + cB];
    }

    const int beg = row_start[n];
    const int end = beg + counts[n];

    float Swd[6] = {0.f, 0.f, 0.f, 0.f, 0.f, 0.f};
    float g0 = 0.f, g1 = 0.f;

    for (int p0 = beg; p0 < end; p0 += 64) {
        const int t = p0 + lane;
        uint2 pe = (t < end) ? pedge[t] : make_uint2(0u, 0u);
        const unsigned dp = pe.y;
        const float nr = (dp != 0u) ? norm[pe.x] : 0.f;

        unsigned zm = 0;
#pragma unroll
        for (int i = 0; i < 6; ++i) {
            int d = (dp >> (4 * i)) & 15;
            if (d == 0) zm |= (1u << i);
            Swd[i] += nr * (float)d;
        }
        const int z = __popc(zm);
        const int ne = (dp == 0u) ? 0 : ((z <= 2) ? (1 + z) : (6 - z));

        int x = ne;
#pragma unroll
        for (int st = 1; st < 64; st <<= 1) {
            int v = __shfl_up(x, st);
            if (lane >= st) x += v;
        }
        const int excl = x - ne;
        const int total = __shfl(x, 63);

        if (ne) {
            const unsigned base = pe.x * (unsigned)PROWB;   // byte offset of P row
            int wp = excl;
            if (z <= 2) {
                el[wp++] = base + 768u;                     // + sum-slice (fp8)
#pragma unroll
                for (int i = 0; i < 6; ++i)
                    if ((zm >> i) & 1u) el[wp++] = (base + i * 128u) | 0x80000000u;  // - zero slices
            } else {
#pragma unroll
                for (int i = 0; i < 6; ++i)
                    if (!((zm >> i) & 1u)) el[wp++] = base + i * 128u;               // + nonzero slices
            }
        }
        asm volatile("s_waitcnt lgkmcnt(0)" ::: "memory");

        int j = 0;
        for (; j + 8 <= total; j += 8) {
            unsigned ev[8];
            unsigned short qv[8];
#pragma unroll
            for (int q = 0; q < 8; ++q)
                ev[q] = __builtin_amdgcn_readfirstlane(el[j + q]);
#pragma unroll
            for (int q = 0; q < 8; ++q)
                qv[q] = *(const unsigned short*)(PG + (ev[q] & 0x7fffffffu) + l2);
#pragma unroll
            for (int q = 0; q < 8; ++q) {
                f32x2 fq = __builtin_amdgcn_cvt_pk_f32_fp8((int)qv[q], false);
                float sg = __uint_as_float(0x3f800000u | (ev[q] & 0x80000000u));
                g0 = fmaf(sg, fq.x, g0);
                g1 = fmaf(sg, fq.y, g1);
            }
        }
        for (; j < total; ++j) {
            unsigned e0 = __builtin_amdgcn_readfirstlane(el[j]);
            unsigned short q0 = *(const unsigned short*)(PG + (e0 & 0x7fffffffu) + l2);
            f32x2 f0 = __builtin_amdgcn_cvt_pk_f32_fp8((int)q0, false);
            float sg = __uint_as_float(0x3f800000u | (e0 & 0x80000000u));
            g0 = fmaf(sg, f0.x, g0);
            g1 = fmaf(sg, f0.y, g1);
        }
    }

    float b0 = 0.f, b1 = 0.f;
#pragma unroll
    for (int i = 0; i < 6; ++i) {
        float v = Swd[i];
#pragma unroll
        for (int st = 1; st < 64; st <<= 1) v += __shfl_xor(v, st);
        b0 = fmaf(v, wA[i], b0);
        b1 = fmaf(v, wB[i], b1);
    }

    const unsigned us = *(const unsigned*)(PG + (size_t)n * PROWB + 896 + lane * 4);
    const float nd = norm[n];
    float o0 = fmaxf((g0 + b0) * nd + bf_lo(us) + bias[cA], 0.f);
    float o1 = fmaxf((g1 + b1) * nd + bf_hi(us) + bias[cB], 0.f);
    out[(size_t)n * OUT_F + cA] = o0;
    out[(size_t)n * OUT_F + cB] = o1;
}

extern "C" void kernel_launch(void* const* d_in, const int* in_sizes, int n_in,
                              void* d_out, int out_size, void* d_ws, size_t ws_size,
                              hipStream_t stream)
{
    const float* h       = (const float*)d_in[0];
    const float* degrees = (const float*)d_in[1];
    const float* norm    = (const float*)d_in[2];
    const int*   src     = (const int*)d_in[3];
    const int*   dst     = (const int*)d_in[4];
    const float* W_self  = (const float*)d_in[5];
    const float* b_self  = (const float*)d_in[6];
    const float* W_node  = (const float*)d_in[7];
    const float* b_node  = (const float*)d_in[8];
    const float* W_edge  = (const float*)d_in[9];
    const float* bias    = (const float*)d_in[10];
    float* out = (float*)d_out;

    const int N = in_sizes[2];   // norm [N,1]
    const int E = in_sizes[3];   // src [E]
    const int NB = (N + 255) / 256;

    char* ws = (char*)d_ws;
    size_t off = 0;
    auto alloc = [&](size_t sz) { size_t o = off; off = (off + sz + 255) & ~(size_t)255; return o; };
    char*           PG     = (char*)(ws + alloc((size_t)N * PROWB));               // 57.6 MB
    unsigned short* hb     = (unsigned short*)(ws + alloc((size_t)N * IN_F * 2));  // 25.6 MB
    unsigned short* Wt     = (unsigned short*)(ws + alloc((size_t)NCOLS * IN_F * 2));
    float*          bvec   = (float*)(ws + alloc(NCOLS * 4));
    int*            counts = (int*)(ws + alloc((size_t)N * 4));
    int*            offs   = (int*)(ws + alloc((size_t)N * 4));
    int*            cursor = (int*)(ws + alloc((size_t)N * 4));
    int*            bsum   = (int*)(ws + alloc((size_t)NB * 4));
    uint2*          pedge  = (uint2*)(ws + alloc((size_t)E * 8));                  // 6.4 MB

    hipMemsetAsync(counts, 0, (size_t)N * 4, stream);

    const int t8 = N * (IN_F / 8);          // 1.6 M
    const int tw = IN_F * NCOLS;            // 256 K
    int prepT = t8; if (tw > prepT) prepT = tw; if (E > prepT) prepT = E;
    k_prep<<<(prepT + 255) / 256, 256, 0, stream>>>(h, hb, t8, W_node, W_self, b_node, b_self,
                                                    Wt, bvec, tw, dst, counts, E);

    const int R  = (N + BM - 1) / BM;
    const int RP = (R + 7) / 8;
    k_gemm<<<RP * 8 * 8, 256, 0, stream>>>(hb, Wt, bvec, norm, PG, N, RP);

    k_scan_a<<<NB, 256, 0, stream>>>(counts, offs, bsum, N);
    k_scan_b<<<1, 256, 0, stream>>>(bsum, NB);
    k_scan_c<<<NB, 256, 0, stream>>>(offs, bsum, cursor, N);
    k_scatter<<<(E + 255) / 256, 256, 0, stream>>>(src, dst, degrees, cursor, pedge, E);

    k_aggregate<<<(N + 3) / 4, 256, 0, stream>>>(PG, offs, counts, pedge,
                                                 norm, W_edge, bias, out, N);
}